// Round 1
// baseline (968.008 us; speedup 1.0000x reference)
//
#include <hip/hip_runtime.h>
#include <hip/hip_bf16.h>
#include <cstdint>

#define H 256
#define BK 32
#define MT 64
#define ROWS 128

typedef _Float16 half8 __attribute__((ext_vector_type(8)));
typedef float floatx4 __attribute__((ext_vector_type(4)));

__device__ __forceinline__ float fast_tanh(float v) {
    v = fminf(fmaxf(v, -15.f), 15.f);
    float e = __expf(2.f * v);
    return (e - 1.f) / (e + 1.f);
}

// ---------------- init: zero out accumulator + maxv + sumexp ----------------
__global__ void init_kernel(float* __restrict__ out, int* __restrict__ maxv,
                            float* __restrict__ sumexp, int G, int total) {
    int i = blockIdx.x * 256 + threadIdx.x;
    if (i < total) out[i] = 0.f;
    if (i < G) { maxv[i] = 0; sumexp[i] = 0.f; }
}

// ---------------- W1 [k][j] fp32 -> w1c [j][k] f16 (B-operand layout) -------
__global__ void w1conv_kernel(const float* __restrict__ W1, _Float16* __restrict__ w1c) {
    int i = blockIdx.x * 256 + threadIdx.x;  // i = j*H + k
    if (i < H * H) {
        int j = i >> 8, k = i & 255;
        w1c[i] = (_Float16)W1[k * H + j];
    }
}

// ---------------- scores = tanh(x@W1 + b1) @ w2 -----------------------------
// block: 256 thr (4 waves). tile: 64 rows x 256 cols. wave w owns cols [64w,64w+64).
// A staged in LDS (fp32->f16, XOR-swizzled 16B groups for conflict-free b128 reads).
// B read directly from L2-resident w1c (16B/lane loads).
__global__ __launch_bounds__(256) void scores_kernel(
    const float* __restrict__ x, const _Float16* __restrict__ w1c,
    const float* __restrict__ b1, const float* __restrict__ w2,
    float* __restrict__ scores, int N) {
    __shared__ _Float16 As[MT][BK];
    __shared__ float sred[4][MT];

    const int tid = threadIdx.x;
    const int wv = tid >> 6;
    const int lane = tid & 63;
    const int m = lane & 15;
    const int q = lane >> 4;
    const int row0 = blockIdx.x * MT;

    floatx4 acc[4][4] = {};

    const int r_st = tid >> 2;                 // staging row 0..63
    const int g_st = tid & 3;                  // 16B group within row
    const int gs = g_st ^ ((r_st >> 1) & 3);   // swizzled group
    const int rg = q ^ ((m >> 1) & 3);         // read-side swizzle

    for (int kk = 0; kk < H; kk += BK) {
        float4 f0, f1;
        int grow = row0 + r_st;
        if (grow < N) {
            const float* src = x + (size_t)grow * H + kk + g_st * 8;
            f0 = *(const float4*)src;
            f1 = *(const float4*)(src + 4);
        } else {
            f0 = make_float4(0.f, 0.f, 0.f, 0.f);
            f1 = f0;
        }
        half8 hv;
        hv[0] = (_Float16)f0.x; hv[1] = (_Float16)f0.y;
        hv[2] = (_Float16)f0.z; hv[3] = (_Float16)f0.w;
        hv[4] = (_Float16)f1.x; hv[5] = (_Float16)f1.y;
        hv[6] = (_Float16)f1.z; hv[7] = (_Float16)f1.w;
        __syncthreads();  // previous iter's reads done
        *(half8*)&As[r_st][gs * 8] = hv;
        __syncthreads();

        half8 af[4];
#pragma unroll
        for (int mi = 0; mi < 4; ++mi)
            af[mi] = *(const half8*)&As[mi * 16 + m][rg * 8];
        half8 bf[4];
#pragma unroll
        for (int ni = 0; ni < 4; ++ni) {
            int c = wv * 64 + ni * 16 + m;
            bf[ni] = *(const half8*)(w1c + (size_t)c * H + kk + q * 8);
        }
#pragma unroll
        for (int mi = 0; mi < 4; ++mi)
#pragma unroll
            for (int ni = 0; ni < 4; ++ni)
                acc[mi][ni] = __builtin_amdgcn_mfma_f32_16x16x32_f16(
                    af[mi], bf[ni], acc[mi][ni], 0, 0, 0);
    }

    // epilogue: s_row = sum_j w2[j] * tanh(h[row][j] + b1[j])
    float b1c[4], w2c[4];
#pragma unroll
    for (int ni = 0; ni < 4; ++ni) {
        int c = wv * 64 + ni * 16 + m;
        b1c[ni] = b1[c];
        w2c[ni] = w2[c];
    }
#pragma unroll
    for (int mi = 0; mi < 4; ++mi) {
#pragma unroll
        for (int r = 0; r < 4; ++r) {
            float v = 0.f;
#pragma unroll
            for (int ni = 0; ni < 4; ++ni)
                v += w2c[ni] * fast_tanh(acc[mi][ni][r] + b1c[ni]);
            v += __shfl_xor(v, 1);
            v += __shfl_xor(v, 2);
            v += __shfl_xor(v, 4);
            v += __shfl_xor(v, 8);
            if (m == 0) sred[wv][mi * 16 + q * 4 + r] = v;
        }
    }
    __syncthreads();
    if (tid < MT) {
        int row = row0 + tid;
        if (row < N)
            scores[row] = sred[0][tid] + sred[1][tid] + sred[2][tid] + sred[3][tid];
    }
}

// ---------------- segment max (clamped below at 0) --------------------------
__global__ void segmax_kernel(const float* __restrict__ scores,
                              const int* __restrict__ batch,
                              int* __restrict__ maxv, int N) {
    int i = blockIdx.x * 256 + threadIdx.x;
    if (i < N) {
        float s = scores[i];
        if (s > 0.f) atomicMax(&maxv[batch[i]], __float_as_int(s));
    }
}

// ---------------- weighted segment sum + sumexp -----------------------------
// block: 256 thr, thread t owns column t. ROWS consecutive (sorted) rows.
// register accumulate within a graph run, atomicAdd flush at boundaries.
__global__ __launch_bounds__(256) void pass2_kernel(
    const float* __restrict__ x, const int* __restrict__ batch,
    const float* __restrict__ scores, const int* __restrict__ maxv,
    float* __restrict__ out, float* __restrict__ sumexp, int N) {
    const int t = threadIdx.x;
    int i0 = blockIdx.x * ROWS;
    if (i0 >= N) return;
    int i1 = min(i0 + ROWS, N);

    float acc = 0.f, sw = 0.f;
    int cur = batch[i0];

    // prefetch row i0
    float xv = x[(size_t)i0 * H + t];
    int g = cur;
    float w = __expf(scores[i0] - __int_as_float(maxv[g]));

    for (int i = i0; i < i1; ++i) {
        float xv_n = 0.f, w_n = 0.f;
        int g_n = cur;
        if (i + 1 < i1) {
            xv_n = x[(size_t)(i + 1) * H + t];
            g_n = batch[i + 1];
            w_n = __expf(scores[i + 1] - __int_as_float(maxv[g_n]));
        }
        if (g != cur) {
            atomicAdd(&out[(size_t)cur * H + t], acc);
            if (t == 0) atomicAdd(&sumexp[cur], sw);
            acc = 0.f;
            sw = 0.f;
            cur = g;
        }
        acc = fmaf(w, xv, acc);
        if (t == 0) sw += w;
        xv = xv_n; g = g_n; w = w_n;
    }
    atomicAdd(&out[(size_t)cur * H + t], acc);
    if (t == 0) atomicAdd(&sumexp[cur], sw);
}

// ---------------- normalize in place ----------------------------------------
__global__ void normalize_kernel(float* __restrict__ out,
                                 const float* __restrict__ sumexp, int total) {
    int i = blockIdx.x * 256 + threadIdx.x;
    if (i < total) {
        float s = sumexp[i >> 8];
        out[i] = (s > 0.f) ? out[i] / s : 0.f;
    }
}

extern "C" void kernel_launch(void* const* d_in, const int* in_sizes, int n_in,
                              void* d_out, int out_size, void* d_ws, size_t ws_size,
                              hipStream_t stream) {
    const float* x = (const float*)d_in[0];
    const int* batch = (const int*)d_in[1];
    const float* W1 = (const float*)d_in[2];
    const float* b1 = (const float*)d_in[3];
    const float* w2 = (const float*)d_in[4];
    float* out = (float*)d_out;

    const int N = in_sizes[0] / H;
    const int G = out_size / H;

    char* ws = (char*)d_ws;
    float* scores = (float*)ws;
    size_t off = (size_t)N * sizeof(float);
    off = (off + 15) & ~(size_t)15;
    int* maxv = (int*)(ws + off);
    off += (size_t)G * sizeof(int);
    float* sumexp = (float*)(ws + off);
    off += (size_t)G * sizeof(float);
    off = (off + 15) & ~(size_t)15;
    _Float16* w1c = (_Float16*)(ws + off);

    int total = G * H;
    init_kernel<<<(total + 255) / 256, 256, 0, stream>>>(out, maxv, sumexp, G, total);
    w1conv_kernel<<<(H * H + 255) / 256, 256, 0, stream>>>(W1, w1c);
    scores_kernel<<<(N + MT - 1) / MT, 256, 0, stream>>>(x, w1c, b1, w2, scores, N);
    segmax_kernel<<<(N + 255) / 256, 256, 0, stream>>>(scores, batch, maxv, N);
    pass2_kernel<<<(N + ROWS - 1) / ROWS, 256, 0, stream>>>(x, batch, scores, maxv, out, sumexp, N);
    normalize_kernel<<<(total + 255) / 256, 256, 0, stream>>>(out, sumexp, total);
}

// Round 2
// 912.422 us; speedup vs baseline: 1.0609x; 1.0609x over previous
//
#include <hip/hip_runtime.h>
#include <cstdint>

#define H 256
#define MT 64
#define ROWS 256

typedef _Float16 half8 __attribute__((ext_vector_type(8)));
typedef float floatx4 __attribute__((ext_vector_type(4)));

__device__ __forceinline__ float fast_tanh(float v) {
    v = fminf(fmaxf(v, -15.f), 15.f);
    float e = __expf(2.f * v);
    return (e - 1.f) / (e + 1.f);
}

// ---------------- init: zero out accumulator + maxv + sumexp ----------------
__global__ void init_kernel(float4* __restrict__ out4, int* __restrict__ maxv,
                            float* __restrict__ sumexp, int G, int total4) {
    int i = blockIdx.x * 256 + threadIdx.x;
    if (i < total4) out4[i] = make_float4(0.f, 0.f, 0.f, 0.f);
    if (i < G) { maxv[i] = 0; sumexp[i] = 0.f; }
}

// ---------------- W1 [k][n] fp32 -> w1c f16 in MFMA B-fragment order --------
// chunk t = ((ct*4 + s)*2 + kc), each 512 halves: [lane][h]
//   element = W1[k = s*64 + kc*32 + (lane>>4)*8 + h][n = ct*16 + (lane&15)]
__global__ void w1conv_kernel(const float* __restrict__ W1, _Float16* __restrict__ w1c) {
    int i = blockIdx.x * 256 + threadIdx.x;
    if (i < H * H) {
        int r = i & 511;
        int lane = r >> 3, h = r & 7;
        int t = i >> 9;
        int kc = t & 1, s = (t >> 1) & 3, ct = t >> 3;
        int mm = lane & 15, qq = lane >> 4;
        int col = ct * 16 + mm;
        int k = s * 64 + kc * 32 + qq * 8 + h;
        w1c[i] = (_Float16)W1[k * H + col];
    }
}

// ---------------- scores = tanh(x@W1 + b1) @ w2 ; fused segment atomicMax ---
// 256 thr (4 waves), tile 64 rows x 256 cols, BK=64 (4 k-steps),
// double-buffered swizzled LDS for A, coalesced fragment-order B from L2.
__global__ __launch_bounds__(256, 3) void scores_kernel(
    const float* __restrict__ x, const _Float16* __restrict__ w1c,
    const float* __restrict__ b1, const float* __restrict__ w2,
    const int* __restrict__ batch,
    float* __restrict__ scores, int* __restrict__ maxv, int N) {
    __shared__ _Float16 As[2][64][64];
    __shared__ float sred[4][64];

    const int tid = threadIdx.x;
    const int wv = tid >> 6;
    const int lane = tid & 63;
    const int m = lane & 15;
    const int q = lane >> 4;
    const int row0 = blockIdx.x * MT;

    // staging assignment: thread -> (row, 16-float chunk)
    const int srow = tid >> 2;
    const int sc4 = tid & 3;
    const int sg0 = (sc4 * 2) ^ (srow & 7);       // swizzled 8-half groups
    const int sg1 = (sc4 * 2 + 1) ^ (srow & 7);
    const bool srok = (row0 + srow) < N;
    const float* sbase = x + (size_t)(row0 + srow) * H + sc4 * 16;

    floatx4 acc[4][4] = {};

    float4 f0, f1, f2, f3;
    f0 = f1 = f2 = f3 = make_float4(0.f, 0.f, 0.f, 0.f);
    if (srok) {
        const float4* p = (const float4*)sbase;
        f0 = p[0]; f1 = p[1]; f2 = p[2]; f3 = p[3];
    }
    {
        half8 h0, h1;
        h0[0] = (_Float16)f0.x; h0[1] = (_Float16)f0.y; h0[2] = (_Float16)f0.z; h0[3] = (_Float16)f0.w;
        h0[4] = (_Float16)f1.x; h0[5] = (_Float16)f1.y; h0[6] = (_Float16)f1.z; h0[7] = (_Float16)f1.w;
        h1[0] = (_Float16)f2.x; h1[1] = (_Float16)f2.y; h1[2] = (_Float16)f2.z; h1[3] = (_Float16)f2.w;
        h1[4] = (_Float16)f3.x; h1[5] = (_Float16)f3.y; h1[6] = (_Float16)f3.z; h1[7] = (_Float16)f3.w;
        *(half8*)&As[0][srow][sg0 * 8] = h0;
        *(half8*)&As[0][srow][sg1 * 8] = h1;
    }
    __syncthreads();

    for (int s = 0; s < 4; ++s) {
        const int cur = s & 1;
        // issue next tile's global loads EARLY (overlap with B loads + MFMA)
        if (s < 3 && srok) {
            const float4* p = (const float4*)(sbase + (s + 1) * 64);
            f0 = p[0]; f1 = p[1]; f2 = p[2]; f3 = p[3];
        }
        // B fragments: fully coalesced 16B/lane from L2-resident w1c
        half8 bf[4][2];
#pragma unroll
        for (int ni = 0; ni < 4; ++ni) {
            int ct = wv * 4 + ni;
#pragma unroll
            for (int kc = 0; kc < 2; ++kc) {
                int chunk = ((ct << 2) | s) * 2 + kc;
                bf[ni][kc] = *(const half8*)(w1c + ((size_t)chunk << 9) + lane * 8);
            }
        }
        // A fragments from swizzled LDS
        half8 af[4][2];
#pragma unroll
        for (int mi = 0; mi < 4; ++mi) {
            int r = mi * 16 + m;
#pragma unroll
            for (int kc = 0; kc < 2; ++kc) {
                int g = (kc * 4 + q) ^ (r & 7);
                af[mi][kc] = *(const half8*)&As[cur][r][g * 8];
            }
        }
#pragma unroll
        for (int mi = 0; mi < 4; ++mi)
#pragma unroll
            for (int ni = 0; ni < 4; ++ni) {
                acc[mi][ni] = __builtin_amdgcn_mfma_f32_16x16x32_f16(
                    af[mi][0], bf[ni][0], acc[mi][ni], 0, 0, 0);
                acc[mi][ni] = __builtin_amdgcn_mfma_f32_16x16x32_f16(
                    af[mi][1], bf[ni][1], acc[mi][ni], 0, 0, 0);
            }
        if (s < 3) {
            half8 h0, h1;
            h0[0] = (_Float16)f0.x; h0[1] = (_Float16)f0.y; h0[2] = (_Float16)f0.z; h0[3] = (_Float16)f0.w;
            h0[4] = (_Float16)f1.x; h0[5] = (_Float16)f1.y; h0[6] = (_Float16)f1.z; h0[7] = (_Float16)f1.w;
            h1[0] = (_Float16)f2.x; h1[1] = (_Float16)f2.y; h1[2] = (_Float16)f2.z; h1[3] = (_Float16)f2.w;
            h1[4] = (_Float16)f3.x; h1[5] = (_Float16)f3.y; h1[6] = (_Float16)f3.z; h1[7] = (_Float16)f3.w;
            *(half8*)&As[1 - cur][srow][sg0 * 8] = h0;
            *(half8*)&As[1 - cur][srow][sg1 * 8] = h1;
        }
        __syncthreads();
    }

    // epilogue: s_row = sum_j w2[j] * tanh(h[row][j] + b1[j])
    float b1c[4], w2c[4];
#pragma unroll
    for (int ni = 0; ni < 4; ++ni) {
        int c = wv * 64 + ni * 16 + m;
        b1c[ni] = b1[c];
        w2c[ni] = w2[c];
    }
#pragma unroll
    for (int mi = 0; mi < 4; ++mi) {
#pragma unroll
        for (int r = 0; r < 4; ++r) {
            float v = 0.f;
#pragma unroll
            for (int ni = 0; ni < 4; ++ni)
                v += w2c[ni] * fast_tanh(acc[mi][ni][r] + b1c[ni]);
            v += __shfl_xor(v, 1);
            v += __shfl_xor(v, 2);
            v += __shfl_xor(v, 4);
            v += __shfl_xor(v, 8);
            if (m == 0) sred[wv][mi * 16 + q * 4 + r] = v;
        }
    }
    __syncthreads();
    if (tid < MT) {
        int row = row0 + tid;
        if (row < N) {
            float sc = sred[0][tid] + sred[1][tid] + sred[2][tid] + sred[3][tid];
            scores[row] = sc;
            if (sc > 0.f) atomicMax(&maxv[batch[row]], __float_as_int(sc));
        }
    }
}

// ---------------- weighted segment sum + sumexp -----------------------------
// 4 waves/block = 4 interleaved row-streams; lane owns 4 columns (float4).
__global__ __launch_bounds__(256) void pass2_kernel(
    const float* __restrict__ x, const int* __restrict__ batch,
    const float* __restrict__ scores, const int* __restrict__ maxv,
    float* __restrict__ out, float* __restrict__ sumexp, int N) {
    const int t = threadIdx.x;
    const int sub = t >> 6;
    const int lane = t & 63;
    const int base = blockIdx.x * ROWS;
    const int i1 = min(base + ROWS, N);
    int i = base + sub;
    if (i >= i1) return;

    const float4* x4 = (const float4*)x;

    float ax = 0.f, ay = 0.f, az = 0.f, aw = 0.f, sw = 0.f;
    int cur = batch[i];
    int g = cur;
    float4 xv = x4[(size_t)i * 64 + lane];
    float w = __expf(scores[i] - __int_as_float(maxv[cur]));

    while (i < i1) {
        int inx = i + 4;
        float4 xv_n = make_float4(0.f, 0.f, 0.f, 0.f);
        float w_n = 0.f;
        int g_n = g;
        if (inx < i1) {
            xv_n = x4[(size_t)inx * 64 + lane];
            g_n = batch[inx];
            w_n = __expf(scores[inx] - __int_as_float(maxv[g_n]));
        }
        if (g != cur) {
            float* o = out + (size_t)cur * H + lane * 4;
            atomicAdd(o + 0, ax); atomicAdd(o + 1, ay);
            atomicAdd(o + 2, az); atomicAdd(o + 3, aw);
            if (lane == 0) atomicAdd(&sumexp[cur], sw);
            ax = ay = az = aw = 0.f; sw = 0.f;
            cur = g;
        }
        ax = fmaf(w, xv.x, ax);
        ay = fmaf(w, xv.y, ay);
        az = fmaf(w, xv.z, az);
        aw = fmaf(w, xv.w, aw);
        if (lane == 0) sw += w;
        xv = xv_n; w = w_n; g = g_n;
        i = inx;
    }
    float* o = out + (size_t)cur * H + lane * 4;
    atomicAdd(o + 0, ax); atomicAdd(o + 1, ay);
    atomicAdd(o + 2, az); atomicAdd(o + 3, aw);
    if (lane == 0) atomicAdd(&sumexp[cur], sw);
}

// ---------------- normalize in place ----------------------------------------
__global__ void normalize_kernel(float4* __restrict__ out4,
                                 const float* __restrict__ sumexp, int total4) {
    int i = blockIdx.x * 256 + threadIdx.x;
    if (i < total4) {
        float s = sumexp[i >> 6];
        if (s > 0.f) {
            float inv = 1.f / s;
            float4 v = out4[i];
            v.x *= inv; v.y *= inv; v.z *= inv; v.w *= inv;
            out4[i] = v;
        } else {
            out4[i] = make_float4(0.f, 0.f, 0.f, 0.f);
        }
    }
}

extern "C" void kernel_launch(void* const* d_in, const int* in_sizes, int n_in,
                              void* d_out, int out_size, void* d_ws, size_t ws_size,
                              hipStream_t stream) {
    const float* x = (const float*)d_in[0];
    const int* batch = (const int*)d_in[1];
    const float* W1 = (const float*)d_in[2];
    const float* b1 = (const float*)d_in[3];
    const float* w2 = (const float*)d_in[4];
    float* out = (float*)d_out;

    const int N = in_sizes[0] / H;
    const int G = out_size / H;

    char* ws = (char*)d_ws;
    float* scores = (float*)ws;
    size_t off = (size_t)N * sizeof(float);
    off = (off + 15) & ~(size_t)15;
    int* maxv = (int*)(ws + off);
    off += (size_t)G * sizeof(int);
    float* sumexp = (float*)(ws + off);
    off += (size_t)G * sizeof(float);
    off = (off + 15) & ~(size_t)15;
    _Float16* w1c = (_Float16*)(ws + off);

    const int total4 = (G * H) / 4;
    init_kernel<<<(max(total4, G) + 255) / 256, 256, 0, stream>>>(
        (float4*)out, maxv, sumexp, G, total4);
    w1conv_kernel<<<(H * H + 255) / 256, 256, 0, stream>>>(W1, w1c);
    scores_kernel<<<(N + MT - 1) / MT, 256, 0, stream>>>(
        x, w1c, b1, w2, batch, scores, maxv, N);
    pass2_kernel<<<(N + ROWS - 1) / ROWS, 256, 0, stream>>>(
        x, batch, scores, maxv, out, sumexp, N);
    normalize_kernel<<<(total4 + 255) / 256, 256, 0, stream>>>(
        (float4*)out, sumexp, total4);
}

// Round 3
// 823.714 us; speedup vs baseline: 1.1752x; 1.1077x over previous
//
#include <hip/hip_runtime.h>
#include <cstdint>

#define H 256
#define MT 64

typedef _Float16 half8 __attribute__((ext_vector_type(8)));
typedef float floatx4 __attribute__((ext_vector_type(4)));

__device__ __forceinline__ float fast_tanh(float v) {
    v = fminf(fmaxf(v, -15.f), 15.f);
    float e = __expf(2.f * v);
    return (e - 1.f) / (e + 1.f);
}

// -------- setup: zero out + Z, and W1 [k][n] fp32 -> w1c f16 fragment order -
// w1c chunk t = ((ct*4 + s)*2 + kc), each 512 halves laid out [lane][h]:
//   element = W1[k = s*64 + kc*32 + (lane>>4)*8 + h][n = ct*16 + (lane&15)]
__global__ void setup_kernel(const float* __restrict__ W1,
                             float4* __restrict__ out4, float* __restrict__ Z,
                             _Float16* __restrict__ w1c, int total4, int G) {
    int i = blockIdx.x * 256 + threadIdx.x;
    if (i < total4) out4[i] = make_float4(0.f, 0.f, 0.f, 0.f);
    if (i < G) Z[i] = 0.f;
    if (i < H * H) {
        int r = i & 511;
        int lane = r >> 3, h = r & 7;
        int t = i >> 9;
        int kc = t & 1, s = (t >> 1) & 3, ct = t >> 3;
        int mm = lane & 15, qq = lane >> 4;
        int col = ct * 16 + mm;
        int k = s * 64 + kc * 32 + qq * 8 + h;
        w1c[i] = (_Float16)W1[k * H + col];
    }
}

// -------- fused: scores GEMM + exp + weighted segment accumulate ------------
// 256 thr (4 waves), tile 64 rows x 256 cols, BK=64 (4 k-steps),
// double-buffered swizzled LDS for A, coalesced fragment-order B from L2.
// Phase B: thread c owns column c; sweeps the (L2-hot) 64 rows accumulating
// e^{s_r} * x[r][c]; flushes at sorted-graph boundaries with atomics.
__global__ __launch_bounds__(256, 3) void fused_kernel(
    const float* __restrict__ x, const _Float16* __restrict__ w1c,
    const float* __restrict__ b1, const float* __restrict__ w2,
    const int* __restrict__ batch,
    float* __restrict__ out, float* __restrict__ Z, int N) {
    __shared__ _Float16 As[2][64][64];
    __shared__ float sred[4][64];
    __shared__ float sexp[64];
    __shared__ int gid[64];

    const int tid = threadIdx.x;
    const int wv = tid >> 6;
    const int lane = tid & 63;
    const int m = lane & 15;
    const int q = lane >> 4;
    const int row0 = blockIdx.x * MT;

    // staging assignment: thread -> (row, 16-float chunk)
    const int srow = tid >> 2;
    const int sc4 = tid & 3;
    const int sg0 = (sc4 * 2) ^ (srow & 7);       // swizzled 8-half groups
    const int sg1 = (sc4 * 2 + 1) ^ (srow & 7);
    const bool srok = (row0 + srow) < N;
    const float* sbase = x + (size_t)(row0 + srow) * H + sc4 * 16;

    floatx4 acc[4][4] = {};

    float4 f0, f1, f2, f3;
    f0 = f1 = f2 = f3 = make_float4(0.f, 0.f, 0.f, 0.f);
    if (srok) {
        const float4* p = (const float4*)sbase;
        f0 = p[0]; f1 = p[1]; f2 = p[2]; f3 = p[3];
    }
    {
        half8 h0, h1;
        h0[0] = (_Float16)f0.x; h0[1] = (_Float16)f0.y; h0[2] = (_Float16)f0.z; h0[3] = (_Float16)f0.w;
        h0[4] = (_Float16)f1.x; h0[5] = (_Float16)f1.y; h0[6] = (_Float16)f1.z; h0[7] = (_Float16)f1.w;
        h1[0] = (_Float16)f2.x; h1[1] = (_Float16)f2.y; h1[2] = (_Float16)f2.z; h1[3] = (_Float16)f2.w;
        h1[4] = (_Float16)f3.x; h1[5] = (_Float16)f3.y; h1[6] = (_Float16)f3.z; h1[7] = (_Float16)f3.w;
        *(half8*)&As[0][srow][sg0 * 8] = h0;
        *(half8*)&As[0][srow][sg1 * 8] = h1;
    }
    __syncthreads();

    for (int s = 0; s < 4; ++s) {
        const int cur = s & 1;
        // issue next tile's global loads EARLY (overlap with B loads + MFMA)
        if (s < 3 && srok) {
            const float4* p = (const float4*)(sbase + (s + 1) * 64);
            f0 = p[0]; f1 = p[1]; f2 = p[2]; f3 = p[3];
        }
        // B fragments: fully coalesced 16B/lane from L2-resident w1c
        half8 bf[4][2];
#pragma unroll
        for (int ni = 0; ni < 4; ++ni) {
            int ct = wv * 4 + ni;
#pragma unroll
            for (int kc = 0; kc < 2; ++kc) {
                int chunk = ((ct << 2) | s) * 2 + kc;
                bf[ni][kc] = *(const half8*)(w1c + ((size_t)chunk << 9) + lane * 8);
            }
        }
        // A fragments from swizzled LDS
        half8 af[4][2];
#pragma unroll
        for (int mi = 0; mi < 4; ++mi) {
            int r = mi * 16 + m;
#pragma unroll
            for (int kc = 0; kc < 2; ++kc) {
                int g = (kc * 4 + q) ^ (r & 7);
                af[mi][kc] = *(const half8*)&As[cur][r][g * 8];
            }
        }
#pragma unroll
        for (int mi = 0; mi < 4; ++mi)
#pragma unroll
            for (int ni = 0; ni < 4; ++ni) {
                acc[mi][ni] = __builtin_amdgcn_mfma_f32_16x16x32_f16(
                    af[mi][0], bf[ni][0], acc[mi][ni], 0, 0, 0);
                acc[mi][ni] = __builtin_amdgcn_mfma_f32_16x16x32_f16(
                    af[mi][1], bf[ni][1], acc[mi][ni], 0, 0, 0);
            }
        if (s < 3) {
            half8 h0, h1;
            h0[0] = (_Float16)f0.x; h0[1] = (_Float16)f0.y; h0[2] = (_Float16)f0.z; h0[3] = (_Float16)f0.w;
            h0[4] = (_Float16)f1.x; h0[5] = (_Float16)f1.y; h0[6] = (_Float16)f1.z; h0[7] = (_Float16)f1.w;
            h1[0] = (_Float16)f2.x; h1[1] = (_Float16)f2.y; h1[2] = (_Float16)f2.z; h1[3] = (_Float16)f2.w;
            h1[4] = (_Float16)f3.x; h1[5] = (_Float16)f3.y; h1[6] = (_Float16)f3.z; h1[7] = (_Float16)f3.w;
            *(half8*)&As[1 - cur][srow][sg0 * 8] = h0;
            *(half8*)&As[1 - cur][srow][sg1 * 8] = h1;
        }
        __syncthreads();
    }

    // epilogue: s_row = sum_j w2[j] * tanh(h[row][j] + b1[j])
    float b1c[4], w2c[4];
#pragma unroll
    for (int ni = 0; ni < 4; ++ni) {
        int c = wv * 64 + ni * 16 + m;
        b1c[ni] = b1[c];
        w2c[ni] = w2[c];
    }
#pragma unroll
    for (int mi = 0; mi < 4; ++mi) {
#pragma unroll
        for (int r = 0; r < 4; ++r) {
            float v = 0.f;
#pragma unroll
            for (int ni = 0; ni < 4; ++ni)
                v += w2c[ni] * fast_tanh(acc[mi][ni][r] + b1c[ni]);
            v += __shfl_xor(v, 1);
            v += __shfl_xor(v, 2);
            v += __shfl_xor(v, 4);
            v += __shfl_xor(v, 8);
            if (m == 0) sred[wv][mi * 16 + q * 4 + r] = v;
        }
    }
    __syncthreads();
    // per-row: score -> exp weight; graph id  (max cancels in U/Z: no segmax)
    if (tid < MT) {
        int row = row0 + tid;
        if (row < N) {
            float sc = sred[0][tid] + sred[1][tid] + sred[2][tid] + sred[3][tid];
            sexp[tid] = __expf(sc);          // |sc| <= sum|w2| ~ 13: no overflow
            gid[tid] = batch[row];
        } else {
            sexp[tid] = 0.f;                 // contributes nothing
            gid[tid] = batch[N - 1];         // valid id, avoids spurious flush
        }
    }
    __syncthreads();

    // Phase B: weighted segment accumulate. Thread tid owns column tid.
    // x rows just streamed -> L2-hot. Flush branch is block-uniform.
    const int nval = min(MT, N - row0);
    const float* px = x + (size_t)row0 * H + tid;
    float acc2 = 0.f, zacc = 0.f;
    int cur = gid[0];
#pragma unroll 4
    for (int r = 0; r < nval; ++r) {
        int g = gid[r];
        float w = sexp[r];
        float xv = px[(size_t)r * H];
        if (g != cur) {
            atomicAdd(&out[(size_t)cur * H + tid], acc2);
            if (tid == 0) atomicAdd(&Z[cur], zacc);
            acc2 = 0.f; zacc = 0.f; cur = g;
        }
        acc2 = fmaf(w, xv, acc2);
        zacc += w;
    }
    atomicAdd(&out[(size_t)cur * H + tid], acc2);
    if (tid == 0) atomicAdd(&Z[cur], zacc);
}

// -------- normalize in place ------------------------------------------------
__global__ void normalize_kernel(float4* __restrict__ out4,
                                 const float* __restrict__ Z, int total4) {
    int i = blockIdx.x * 256 + threadIdx.x;
    if (i < total4) {
        float s = Z[i >> 6];
        if (s > 0.f) {
            float inv = 1.f / s;
            float4 v = out4[i];
            v.x *= inv; v.y *= inv; v.z *= inv; v.w *= inv;
            out4[i] = v;
        } else {
            out4[i] = make_float4(0.f, 0.f, 0.f, 0.f);
        }
    }
}

extern "C" void kernel_launch(void* const* d_in, const int* in_sizes, int n_in,
                              void* d_out, int out_size, void* d_ws, size_t ws_size,
                              hipStream_t stream) {
    const float* x = (const float*)d_in[0];
    const int* batch = (const int*)d_in[1];
    const float* W1 = (const float*)d_in[2];
    const float* b1 = (const float*)d_in[3];
    const float* w2 = (const float*)d_in[4];
    float* out = (float*)d_out;

    const int N = in_sizes[0] / H;
    const int G = out_size / H;

    char* ws = (char*)d_ws;
    float* Z = (float*)ws;
    size_t off = (size_t)G * sizeof(float);
    off = (off + 15) & ~(size_t)15;
    _Float16* w1c = (_Float16*)(ws + off);

    const int total4 = (G * H) / 4;
    int setup_items = max(total4, H * H);
    setup_kernel<<<(setup_items + 255) / 256, 256, 0, stream>>>(
        W1, (float4*)out, Z, w1c, total4, G);
    fused_kernel<<<(N + MT - 1) / MT, 256, 0, stream>>>(
        x, w1c, b1, w2, batch, out, Z, N);
    normalize_kernel<<<(total4 + 255) / 256, 256, 0, stream>>>(
        (float4*)out, Z, total4);
}